// Round 5
// baseline (89.590 us; speedup 1.0000x reference)
//
#include <hip/hip_runtime.h>
#include <hip/hip_fp16.h>
#include <math.h>

#define PATCH 41
#define PSIZE (PATCH * PATCH)   // 1681
#define NUM_ANG 8
#define KS 16
#define STRIDE 10
#define PAD 4
#define DESC 128
#define CLIPVAL 0.2f

#define ROWQ 11                  // 4-pixel quads per row (last is 1 pixel)
#define NQUAD (PATCH * ROWQ)     // 451
#define PLANE_W2 1722            // plane stride in half2 units: 41 * 42
#define PLANE_H  3444            // plane stride in half units
#define CS_STRIDE 34             // colsum row stride (floats)

__device__ __forceinline__ float block_sum256(float v, float* red, int tid) {
    #pragma unroll
    for (int off = 32; off >= 1; off >>= 1) v += __shfl_xor(v, off);
    __syncthreads();
    if ((tid & 63) == 0) red[tid >> 6] = v;
    __syncthreads();
    return red[0] + red[1] + red[2] + red[3];
}

// gradient -> orientation bins -> two b16 LDS scatter writes
__device__ __forceinline__ void bin_write(__half* harr, int y, int x,
                                          float gx, float gy, float gkv) {
    const float mag = sqrtf(gx * gx + gy * gy + 1e-10f) * gkv * 1024.0f;
    const float gxp = gx + 1e-10f;
    const float ax = fabsf(gxp), ay = fabsf(gy);
    const float mx = fmaxf(fmaxf(ax, ay), 1e-20f);
    const float t  = fminf(ax, ay) / mx;
    const float s  = t * t;
    float r = t * (1.27306897f + s * (-0.42055650f + s * (0.22936229f
                  + s * (-0.10839420f + s * 0.02652810f))));
    if (ay > ax)     r = 2.0f - r;
    if (gxp < 0.0f)  r = 4.0f - r;
    if (gy < 0.0f)   r = 8.0f - r;          // octant units in [0, 8]

    const float bo0f = floorf(r);
    const float f    = r - bo0f;
    const int bo0 = ((int)bo0f) & (NUM_ANG - 1);
    const int bo1 = (bo0 + 1) & (NUM_ANG - 1);

    const int w2 = (y * 42 + x) * 2;
    harr[(bo0 >> 1) * PLANE_H + w2 + (bo0 & 1)] = __float2half((1.0f - f) * mag);
    harr[(bo1 >> 1) * PLANE_H + w2 + (bo1 & 1)] = __float2half(f * mag);
}

__global__ __launch_bounds__(256) void sift_desc_kernel(
    const float* __restrict__ input,
    const float* __restrict__ gk,
    const float* __restrict__ pk,
    float* __restrict__ out)
{
    // planar angle-pair planes: s_arr[pair][41][42] of half2(even-angle, odd-angle)
    __shared__ __half2 s_arr[4 * PLANE_W2];           // 27552 B
    __shared__ float   s_colsum[PATCH * CS_STRIDE];   // 5576 B
    __shared__ float   s_red[4];

    const int tid = threadIdx.x;
    const int b   = blockIdx.x;
    const float* in_p = input + (size_t)b * PSIZE;
    __half* harr = (__half*)s_arr;

    // separable pooling weights: pk = outer(w, w), w >= 0
    float w1r[KS];
    #pragma unroll
    for (int d = 0; d < KS; ++d) w1r[d] = sqrtf(pk[d * KS + d]);

    // ---- phase 0: zero the angle planes (incl. pad column x=41) ----
    {
        float4* z = (float4*)s_arr;                    // 1722 x 16B
        const float4 zero = make_float4(0.f, 0.f, 0.f, 0.f);
        for (int i = tid; i < PLANE_W2; i += 256) z[i] = zero;
    }
    __syncthreads();

    // ---- phase 1: gradients from GLOBAL (VMEM pipe), scatter bins to LDS ----
    for (int q = tid; q < NQUAD; q += 256) {
        const int y  = q / ROWQ;
        const int xq = (q - y * ROWQ) * 4;
        const int ym = max(y - 1, 0), yp = min(y + 1, PATCH - 1);
        const float* cr = in_p + y  * PATCH;
        const float* ur = in_p + ym * PATCH;
        const float* dr = in_p + yp * PATCH;
        const float* gr = gk + y * PATCH;

        if (xq < 40) {           // 4-pixel quad, x = xq..xq+3 (<= 39)
            float c0 = cr[xq], c1 = cr[xq+1], c2 = cr[xq+2], c3 = cr[xq+3];
            float L  = cr[max(xq - 1, 0)];
            float R  = cr[xq + 4];
            float u0 = ur[xq], u1 = ur[xq+1], u2 = ur[xq+2], u3 = ur[xq+3];
            float d0 = dr[xq], d1 = dr[xq+1], d2 = dr[xq+2], d3 = dr[xq+3];
            float g0 = gr[xq], g1 = gr[xq+1], g2 = gr[xq+2], g3 = gr[xq+3];

            bin_write(harr, y, xq,     0.5f*(c1 - L),  0.5f*(d0 - u0), g0);
            bin_write(harr, y, xq + 1, 0.5f*(c2 - c0), 0.5f*(d1 - u1), g1);
            bin_write(harr, y, xq + 2, 0.5f*(c3 - c1), 0.5f*(d2 - u2), g2);
            bin_write(harr, y, xq + 3, 0.5f*(R  - c2), 0.5f*(d3 - u3), g3);
        } else {                 // ragged tail: single pixel x = 40
            const float c = cr[40], L = cr[39];
            const float u = ur[40], d = dr[40];
            bin_write(harr, y, 40, 0.5f*(c - L), 0.5f*(d - u), gr[40]);
        }
    }
    __syncthreads();

    // ---- phase 2a: x-pooling with aligned b64 reads; wave-uniform window j ----
    // thread: pair = tid&3, y-slice y0 = (tid>>2)&15, j = tid>>6 (wave id)
    {
        const int pair = tid & 3;
        const int y0   = (tid >> 2) & 15;
        const int j    = tid >> 6;

        union U64 { float2 f2; __half2 h2[2]; };
        for (int y = y0; y < PATCH; y += 16) {
            float acc0 = 0.0f, acc1 = 0.0f;
            const __half2* rowb = s_arr + pair * PLANE_W2 + y * 42;

            #define XPOOL(PX0, NP, W0)                                          \
                { const __half2* rb = rowb + (PX0);                             \
                  _Pragma("unroll")                                             \
                  for (int np = 0; np < (NP); ++np) {                           \
                      U64 u; u.f2 = *(const float2*)(rb + 2 * np);              \
                      const float wA = w1r[(W0) + 2 * np];                      \
                      const float wB = w1r[(W0) + 2 * np + 1];                  \
                      acc0 = fmaf(wA, __half2float(u.h2[0].x), acc0);           \
                      acc1 = fmaf(wA, __half2float(u.h2[0].y), acc1);           \
                      acc0 = fmaf(wB, __half2float(u.h2[1].x), acc0);           \
                      acc1 = fmaf(wB, __half2float(u.h2[1].y), acc1);           \
                  } }

            switch (j) {     // wave-uniform branch
                case 0: XPOOL(0, 6, 4);  break;   // px 0..11,  w[4..15]
                case 1: XPOOL(6, 8, 0);  break;   // px 6..21,  w[0..15]
                case 2: XPOOL(16, 8, 0); break;   // px 16..31, w[0..15]
                default: XPOOL(26, 8, 0); break;  // px 26..41 (41 = zero pad)
            }
            #undef XPOOL

            *(float2*)(s_colsum + y * CS_STRIDE + j * 8 + pair * 2) =
                make_float2(acc0, acc1);
        }
    }
    __syncthreads();

    // ---- phase 2b: y-pooling -> one descriptor value per tid < 128 ----
    float v = 0.0f;
    int a = 0, jj = 0, ii = 0;
    if (tid < DESC) {
        a = tid & 7; jj = (tid >> 3) & 3; ii = tid >> 5;
        const int py0 = ii * STRIDE - PAD;
        #pragma unroll
        for (int dy = 0; dy < KS; ++dy) {
            const int py  = py0 + dy;
            const int pyc = min(max(py, 0), PATCH - 1);
            const float wv = (py == pyc) ? w1r[dy] : 0.0f;
            v = fmaf(wv, s_colsum[pyc * CS_STRIDE + jj * 8 + a], v);
        }
    }

    // ---- normalization chain: l2n -> clip -> l2n -> rootsift ----
    const float ss1 = block_sum256(v * v, s_red, tid);
    float aa = v / fmaxf(sqrtf(ss1), 1e-12f);
    aa = fminf(fmaxf(aa, 0.0f), CLIPVAL);

    const float ss2 = block_sum256(aa * aa, s_red, tid);
    const float bn = aa / fmaxf(sqrtf(ss2), 1e-12f);

    const float l1 = block_sum256(fabsf(bn), s_red, tid);
    const float o  = sqrtf(bn / fmaxf(l1, 1e-12f) + 1e-10f);

    // reference layout: desc[ang*16 + i*4 + j]
    if (tid < DESC) out[(size_t)b * DESC + (a * 16 + ii * 4 + jj)] = o;
}

extern "C" void kernel_launch(void* const* d_in, const int* in_sizes, int n_in,
                              void* d_out, int out_size, void* d_ws, size_t ws_size,
                              hipStream_t stream) {
    const float* input = (const float*)d_in[0];
    const float* gk    = (const float*)d_in[1];
    const float* pk    = (const float*)d_in[2];
    float* out         = (float*)d_out;

    const int B = in_sizes[0] / PSIZE;
    if (B <= 0) return;
    sift_desc_kernel<<<dim3(B), dim3(256), 0, stream>>>(input, gk, pk, out);
}

// Round 6
// 82.688 us; speedup vs baseline: 1.0835x; 1.0835x over previous
//
#include <hip/hip_runtime.h>
#include <math.h>

#define PATCH 41
#define PSIZE (PATCH * PATCH)   // 1681
#define NUM_ANG 8
#define KS 16
#define STRIDE 10
#define PAD 4
#define DESC 128
#define CLIPVAL 0.2f

#define ROWQ 11                  // 4-pixel quads per row (last is 1 pixel)
#define NQUAD (PATCH * ROWQ)     // 451
#define CS_STRIDE 34             // colsum row stride (floats)

__device__ __forceinline__ float block_sum256(float v, float* red, int tid) {
    #pragma unroll
    for (int off = 32; off >= 1; off >>= 1) v += __shfl_xor(v, off);
    __syncthreads();
    if ((tid & 63) == 0) red[tid >> 6] = v;
    __syncthreads();
    return red[0] + red[1] + red[2] + red[3];
}

// gradient -> (orientation in octant units [0,8], gaussian-weighted magnitude)
__device__ __forceinline__ float2 grad_om(float gx, float gy, float gkv) {
    const float mag = sqrtf(gx * gx + gy * gy + 1e-10f) * gkv;
    const float gxp = gx + 1e-10f;
    const float ax = fabsf(gxp), ay = fabsf(gy);
    const float mx = fmaxf(fmaxf(ax, ay), 1e-20f);
    const float t  = fminf(ax, ay) / mx;
    const float s  = t * t;
    float r = t * (1.27306897f + s * (-0.42055650f + s * (0.22936229f
                  + s * (-0.10839420f + s * 0.02652810f))));
    if (ay > ax)     r = 2.0f - r;
    if (gxp < 0.0f)  r = 4.0f - r;
    if (gy < 0.0f)   r = 8.0f - r;          // in [0, 8]
    return make_float2(r, mag);
}

__global__ __launch_bounds__(256) void sift_desc_kernel(
    const float* __restrict__ input,
    const float* __restrict__ gk,
    const float* __restrict__ pk,
    float* __restrict__ out)
{
    __shared__ float s_o[PSIZE];                    // orientation, octant units
    __shared__ float s_m[PSIZE];                    // weighted magnitude
    __shared__ float s_colsum[PATCH * CS_STRIDE];   // [41][4j][8a] (+pad)
    __shared__ float s_red[4];

    const int tid = threadIdx.x;
    const int b   = blockIdx.x;
    const float* in_p = input + (size_t)b * PSIZE;

    // separable pooling weights: pk = outer(w, w), w >= 0 -> w[d] = sqrt(diag)
    float w1r[KS];
    #pragma unroll
    for (int d = 0; d < KS; ++d) w1r[d] = sqrtf(pk[d * KS + d]);

    // ---- phase 1: gradients from GLOBAL (VMEM pipe) -> (o, m) SoA in LDS ----
    for (int q = tid; q < NQUAD; q += 256) {
        const int y  = q / ROWQ;
        const int xq = (q - y * ROWQ) * 4;
        const int ym = max(y - 1, 0), yp = min(y + 1, PATCH - 1);
        const float* cr = in_p + y  * PATCH;
        const float* ur = in_p + ym * PATCH;
        const float* dr = in_p + yp * PATCH;
        const float* gr = gk + y * PATCH;
        const int p = y * PATCH + xq;

        if (xq < 40) {           // 4-pixel quad, x = xq..xq+3 (<= 39)
            float c0 = cr[xq], c1 = cr[xq+1], c2 = cr[xq+2], c3 = cr[xq+3];
            float L  = cr[max(xq - 1, 0)];
            float R  = cr[xq + 4];
            float u0 = ur[xq], u1 = ur[xq+1], u2 = ur[xq+2], u3 = ur[xq+3];
            float d0 = dr[xq], d1 = dr[xq+1], d2 = dr[xq+2], d3 = dr[xq+3];

            float2 om0 = grad_om(0.5f*(c1 - L),  0.5f*(d0 - u0), gr[xq]);
            float2 om1 = grad_om(0.5f*(c2 - c0), 0.5f*(d1 - u1), gr[xq+1]);
            float2 om2 = grad_om(0.5f*(c3 - c1), 0.5f*(d2 - u2), gr[xq+2]);
            float2 om3 = grad_om(0.5f*(R  - c2), 0.5f*(d3 - u3), gr[xq+3]);
            s_o[p]   = om0.x;  s_m[p]   = om0.y;
            s_o[p+1] = om1.x;  s_m[p+1] = om1.y;
            s_o[p+2] = om2.x;  s_m[p+2] = om2.y;
            s_o[p+3] = om3.x;  s_m[p+3] = om3.y;
        } else {                 // ragged tail: single pixel x = 40
            float2 om = grad_om(0.5f*(cr[40] - cr[39]),
                                0.5f*(dr[40] - ur[40]), gr[40]);
            s_o[p] = om.x;  s_m[p] = om.y;
        }
    }
    __syncthreads();

    // ---- phase 2a: x-pooling; thread (y, j) owns ALL 8 angle accumulators ----
    if (tid < PATCH * 4) {
        const int y  = tid >> 2;
        const int j  = tid & 3;
        const int px0 = j * STRIDE - PAD;
        const float* po = s_o + y * PATCH;
        const float* pm = s_m + y * PATCH;

        float acc[NUM_ANG];
        #pragma unroll
        for (int a = 0; a < NUM_ANG; ++a) acc[a] = 0.0f;

        #pragma unroll
        for (int dx = 0; dx < KS; ++dx) {
            const int px  = px0 + dx;
            const int pxc = min(max(px, 0), PATCH - 1);
            const float wv = (px == pxc) ? w1r[dx] : 0.0f;
            const float o  = po[pxc];
            const float mw = pm[pxc] * wv;
            #pragma unroll
            for (int a = 0; a < NUM_ANG; ++a) {
                const float d  = fabsf(o - (float)a);
                const float dm = fminf(d, 8.0f - d);     // wrapped distance
                const float t  = fmaxf(0.0f, 1.0f - dm); // periodic hat
                acc[a] = fmaf(t, mw, acc[a]);
            }
        }
        #pragma unroll
        for (int a = 0; a < NUM_ANG; ++a)
            s_colsum[y * CS_STRIDE + j * 8 + a] = acc[a];
    }
    __syncthreads();

    // ---- phase 2b: y-pooling -> one descriptor value per tid < 128 ----
    float v = 0.0f;
    int a = 0, jj = 0, ii = 0;
    if (tid < DESC) {
        a = tid & 7; jj = (tid >> 3) & 3; ii = tid >> 5;
        const int py0 = ii * STRIDE - PAD;
        #pragma unroll
        for (int dy = 0; dy < KS; ++dy) {
            const int py  = py0 + dy;
            const int pyc = min(max(py, 0), PATCH - 1);
            const float wv = (py == pyc) ? w1r[dy] : 0.0f;
            v = fmaf(wv, s_colsum[pyc * CS_STRIDE + jj * 8 + a], v);
        }
    }

    // ---- normalization chain: l2n -> clip -> l2n -> rootsift ----
    const float ss1 = block_sum256(v * v, s_red, tid);
    float aa = v / fmaxf(sqrtf(ss1), 1e-12f);
    aa = fminf(fmaxf(aa, 0.0f), CLIPVAL);

    const float ss2 = block_sum256(aa * aa, s_red, tid);
    const float bn = aa / fmaxf(sqrtf(ss2), 1e-12f);

    const float l1 = block_sum256(fabsf(bn), s_red, tid);
    const float o  = sqrtf(bn / fmaxf(l1, 1e-12f) + 1e-10f);

    // reference layout: desc[ang*16 + i*4 + j]
    if (tid < DESC) out[(size_t)b * DESC + (a * 16 + ii * 4 + jj)] = o;
}

extern "C" void kernel_launch(void* const* d_in, const int* in_sizes, int n_in,
                              void* d_out, int out_size, void* d_ws, size_t ws_size,
                              hipStream_t stream) {
    const float* input = (const float*)d_in[0];
    const float* gk    = (const float*)d_in[1];
    const float* pk    = (const float*)d_in[2];
    float* out         = (float*)d_out;

    const int B = in_sizes[0] / PSIZE;
    if (B <= 0) return;
    sift_desc_kernel<<<dim3(B), dim3(256), 0, stream>>>(input, gk, pk, out);
}